// Round 1
// baseline (9.645 us; speedup 1.0000x reference)
//
#include <hip/hip_runtime.h>
#include <math.h>

// Reference collapses to a tiny scalar computation:
//   x4[j] (j=0..3) = conv output at batch 0, chan 0, oh=0, ow=j
//                  = x[0,0,0,2j]*w00 + x[0,0,0,2j+1]*w01
//                  + x[0,0,1,2j]*w10 + x[0,0,1,2j+1]*w11 + conv_b[0]
//   k[p] = |prod_{j<4} cos((x4[j]-prototypes[p,j])*0.5)|,  p<20
//   logits[c] = sum_p k[p]*cls_w[c,p] + cls_b[c],          c<10
//   out = log_softmax(logits)                              (10 floats)
// Everything else in the conv (32768x4x14x14 outputs) is dead.

__global__ void HybridQuanvolution_kernel(const float* __restrict__ x,
                                          const float* __restrict__ conv_w,
                                          const float* __restrict__ conv_b,
                                          const float* __restrict__ prototypes,
                                          const float* __restrict__ cls_w,
                                          const float* __restrict__ cls_b,
                                          float* __restrict__ out) {
    __shared__ float k_sh[20];
    __shared__ float logits_sh[10];
    const int t = threadIdx.x;

    if (t < 20) {
        // conv weights / bias (tiny, every lane loads its own copy; L1 broadcast)
        const float w00 = conv_w[0], w01 = conv_w[1];
        const float w10 = conv_w[2], w11 = conv_w[3];
        const float b0  = conv_b[0];
        float k = 1.0f;
        #pragma unroll
        for (int j = 0; j < 4; ++j) {
            // x is (32768,1,28,28); row 0 = x[0..27], row 1 = x[28..55]
            const float x4 = x[2 * j] * w00 + x[2 * j + 1] * w01 +
                             x[28 + 2 * j] * w10 + x[28 + 2 * j + 1] * w11 + b0;
            const float d = (x4 - prototypes[t * 784 + j]) * 0.5f;
            k *= cosf(d);
        }
        k_sh[t] = fabsf(k);
    }
    __syncthreads();

    if (t < 10) {
        float acc = cls_b[t];
        #pragma unroll
        for (int p = 0; p < 20; ++p) acc += k_sh[p] * cls_w[t * 20 + p];
        logits_sh[t] = acc;
    }
    __syncthreads();

    if (t < 10) {
        // 10-wide log-softmax, each lane redundantly reduces
        float m = -INFINITY;
        #pragma unroll
        for (int c = 0; c < 10; ++c) m = fmaxf(m, logits_sh[c]);
        float s = 0.0f;
        #pragma unroll
        for (int c = 0; c < 10; ++c) s += expf(logits_sh[c] - m);
        out[t] = logits_sh[t] - m - logf(s);
    }
}

extern "C" void kernel_launch(void* const* d_in, const int* in_sizes, int n_in,
                              void* d_out, int out_size, void* d_ws, size_t ws_size,
                              hipStream_t stream) {
    const float* x          = (const float*)d_in[0];
    const float* conv_w     = (const float*)d_in[1];
    const float* conv_b     = (const float*)d_in[2];
    const float* prototypes = (const float*)d_in[3];
    const float* cls_w      = (const float*)d_in[4];
    const float* cls_b      = (const float*)d_in[5];
    float* out = (float*)d_out;

    HybridQuanvolution_kernel<<<1, 64, 0, stream>>>(x, conv_w, conv_b, prototypes,
                                                    cls_w, cls_b, out);
}